// Round 4
// baseline (356.785 us; speedup 1.0000x reference)
//
#include <hip/hip_runtime.h>
#include <hip/hip_bf16.h>
#include <stdint.h>

#define NEG_INF -100000000.0f

typedef __attribute__((ext_vector_type(8))) short bf16x8;
typedef __attribute__((ext_vector_type(4))) float f32x4;

static __device__ __forceinline__ short f2bf(float x) {
    unsigned u = __float_as_uint(x);
    u = u + 0x7FFFu + ((u >> 16) & 1u);
    return (short)(u >> 16);
}

// ---------------- kernel 1: transpose + bf16-convert weights ----------------
// w [256 k][256 c] f32  ->  wt [256 c][256 k] bf16
// w_query additionally scaled by 1/16 (= 1/sqrt(D), exact in bf16).
__global__ void wtrans_kernel(const float* __restrict__ wq, const float* __restrict__ wk,
                              short* __restrict__ wtq, short* __restrict__ wtk) {
    __shared__ float tile[32][33];
    const float* w = blockIdx.z ? wk : wq;
    short* wt = blockIdx.z ? wtk : wtq;
    float scale = blockIdx.z ? 1.0f : 0.0625f;
    int tx = threadIdx.x, ty = threadIdx.y;
    int c0 = blockIdx.x * 32;
    int k0 = blockIdx.y * 32;
#pragma unroll
    for (int i = 0; i < 4; i++)
        tile[ty + i * 8][tx] = w[(k0 + ty + i * 8) * 256 + c0 + tx];
    __syncthreads();
#pragma unroll
    for (int i = 0; i < 4; i++)
        wt[(c0 + ty + i * 8) * 256 + k0 + tx] = f2bf(tile[tx][ty + i * 8] * scale);
}

// ---------------- kernel 2: projection GEMM  X[65536,256] @ W[256,256] -> bf16 ----------------
// Output layout MFMA-fragment swizzled: [b 64][dc 8][row 1024][ks 32] bf16
__global__ __launch_bounds__(512, 4)
void proj_kernel(const float* __restrict__ qin, const float* __restrict__ kin,
                 const short* __restrict__ wtq, const short* __restrict__ wtk,
                 short* __restrict__ Qb, short* __restrict__ Kb) {
    const float* x  = blockIdx.y ? kin : qin;
    const short* wt = blockIdx.y ? wtk : wtq;   // [c 256][k 256] bf16
    short* outp     = blockIdx.y ? Kb  : Qb;

    __shared__ __align__(16) short sbuf[64 * 296];   // 37888 B; staging + dump overlay
    short* xlds = sbuf;                // [64 row][32 k] (4 KB)
    short* wlds = sbuf + 2048;         // [256 c][32 k] (16 KB)

    int t = threadIdx.x;
    int lane = t & 63, w = t >> 6;
    int l15 = lane & 15, g = lane >> 4;
    int rowbase = blockIdx.x * 64;

    f32x4 zero = {0.f, 0.f, 0.f, 0.f};
    f32x4 acc[4][2];
#pragma unroll
    for (int m = 0; m < 4; m++)
#pragma unroll
        for (int n = 0; n < 2; n++) acc[m][n] = zero;

    for (int dc = 0; dc < 8; dc++) {
        __syncthreads();
        {
            int row = t >> 3, seg = t & 7;
            float4 v = *reinterpret_cast<const float4*>(x + (size_t)(rowbase + row) * 256 + dc * 32 + seg * 4);
            short4 bb;
            bb.x = f2bf(v.x); bb.y = f2bf(v.y); bb.z = f2bf(v.z); bb.w = f2bf(v.w);
            *reinterpret_cast<short4*>(&xlds[row * 32 + seg * 4]) = bb;
        }
#pragma unroll
        for (int i = 0; i < 2; i++) {
            int idx = i * 512 + t;
            int c = idx >> 2, seg = idx & 3;
            int4 v = *reinterpret_cast<const int4*>(wt + c * 256 + dc * 32 + seg * 8);
            *reinterpret_cast<int4*>(&wlds[idx * 8]) = v;
        }
        __syncthreads();

        bf16x8 a[4], bfr[2];
#pragma unroll
        for (int m = 0; m < 4; m++)
            a[m] = *reinterpret_cast<const bf16x8*>(&xlds[(m * 16 + l15) * 32 + g * 8]);
#pragma unroll
        for (int n = 0; n < 2; n++) {
            int c = w * 32 + n * 16 + l15;
            bfr[n] = *reinterpret_cast<const bf16x8*>(&wlds[c * 32 + g * 8]);
        }
#pragma unroll
        for (int m = 0; m < 4; m++)
#pragma unroll
            for (int n = 0; n < 2; n++)
                acc[m][n] = __builtin_amdgcn_mfma_f32_16x16x32_bf16(a[m], bfr[n], acc[m][n], 0, 0, 0);
    }

    // dump C tile [64 row][256 col] bf16 to LDS (row stride 296 shorts)
    __syncthreads();
#pragma unroll
    for (int m = 0; m < 4; m++)
#pragma unroll
        for (int n = 0; n < 2; n++) {
            int col = w * 32 + n * 16 + l15;
#pragma unroll
            for (int r = 0; r < 4; r++)
                sbuf[(m * 16 + g * 4 + r) * 296 + col] = f2bf(acc[m][n][r]);
        }
    __syncthreads();

    // write out: contiguous 16B units; global addr = ((b8*8+dc)*1024 + row)*32 + kseg*8
    int b8 = rowbase >> 10;
    int rloc = rowbase & 1023;
#pragma unroll
    for (int o = 0; o < 4; o++) {
        int gu = o * 512 + t;
        int dc = gu >> 8;
        int rem = gu & 255;
        int row = rem >> 2, kseg = rem & 3;
        int4 v = *reinterpret_cast<const int4*>(&sbuf[row * 296 + dc * 32 + kseg * 8]);
        size_t idx = (((size_t)b8 * 8 + dc) * 1024 + rloc + row) * 32 + kseg * 8;
        *reinterpret_cast<int4*>(outp + idx) = v;
    }
}

// ---------------- kernel 3: fused QK^T + tanh-clip + mask + log_softmax ----------------
__global__ __launch_bounds__(512, 4)
void attn_kernel(const short* __restrict__ Qs, const short* __restrict__ Ks,
                 const int* __restrict__ mask, float* __restrict__ out) {
    const int RS = 1028;                               // padded row stride (floats)
    __shared__ __align__(16) float ulds[16 * RS];      // 65792 B -> 2 blocks/CU

    int t = threadIdx.x;
    int lane = t & 63, w = t >> 6;
    int l15 = lane & 15, g = lane >> 4;

    int bid = blockIdx.x;
    int wg = (bid & 7) * 256 + (bid >> 3);
    int b = wg >> 5;
    int brow = (wg & 31) * 32;

    // ---- mask prefetch (flies during QK^T) + bit-compress (mask in {0,1}) ----
    int row = t >> 5;          // 0..15
    int j = t & 31;
    const int* mbase = mask + ((size_t)b * 1024 + brow + row) * 1024 + j * 4;
    int4 mv[16];
#pragma unroll
    for (int m = 0; m < 2; m++)
#pragma unroll
        for (int i = 0; i < 8; i++)
            mv[m * 8 + i] = *reinterpret_cast<const int4*>(mbase + m * 16 * 1024 + i * 128);
    unsigned mb[2];
#pragma unroll
    for (int m = 0; m < 2; m++) {
        unsigned v = 0;
#pragma unroll
        for (int i = 0; i < 8; i++) {
            int4 x = mv[m * 8 + i];
            unsigned nib = (unsigned)(x.x | (x.y << 1) | (x.z << 2) | (x.w << 3));
            v |= nib << (i * 4);
        }
        mb[m] = v;
    }

    const short* qb = Qs + (size_t)b * 8 * 1024 * 32;
    const short* kb = Ks + (size_t)b * 8 * 1024 * 32;

    f32x4 zero = {0.f, 0.f, 0.f, 0.f};
    f32x4 acc[2][8];
#pragma unroll
    for (int m = 0; m < 2; m++)
#pragma unroll
        for (int n = 0; n < 8; n++) acc[m][n] = zero;

    for (int dc = 0; dc < 8; dc++) {
        const short* qc = qb + (size_t)dc * 1024 * 32;
        const short* kc = kb + (size_t)dc * 1024 * 32;
        bf16x8 a0 = *reinterpret_cast<const bf16x8*>(qc + (brow + l15) * 32 + g * 8);
        bf16x8 a1 = *reinterpret_cast<const bf16x8*>(qc + (brow + 16 + l15) * 32 + g * 8);
#pragma unroll
        for (int n = 0; n < 8; n++) {
            bf16x8 bf = *reinterpret_cast<const bf16x8*>(kc + (w * 128 + n * 16 + l15) * 32 + g * 8);
            acc[0][n] = __builtin_amdgcn_mfma_f32_16x16x32_bf16(a0, bf, acc[0][n], 0, 0, 0);
            acc[1][n] = __builtin_amdgcn_mfma_f32_16x16x32_bf16(a1, bf, acc[1][n], 0, 0, 0);
        }
    }

    float* urow = ulds + row * RS;

#pragma unroll
    for (int m = 0; m < 2; m++) {
        __syncthreads();
        // dump fragments -> LDS U[16][1024] (padded)
#pragma unroll
        for (int n = 0; n < 8; n++)
#pragma unroll
            for (int r = 0; r < 4; r++)
                ulds[(g * 4 + r) * RS + w * 128 + n * 16 + l15] = acc[m][n][r];
        __syncthreads();

        // pass 1: tanh-clip + mask + exp-sum (lanes j=0..31 own row t>>5)
        float psum = 0.f;
        unsigned bits = mb[m];
#pragma unroll
        for (int i = 0; i < 8; i++) {
            int col = j * 4 + i * 128;
            float4 u4 = *reinterpret_cast<const float4*>(urow + col);
            float uv[4] = {u4.x, u4.y, u4.z, u4.w};
            float uc[4];
#pragma unroll
            for (int c = 0; c < 4; c++) {
                float e2 = __expf(2.0f * uv[c]);
                float tc = 10.0f - 20.0f / (e2 + 1.0f);   // 10*tanh(u)
                bool msk = (bits >> (i * 4 + c)) & 1;
                uc[c] = msk ? NEG_INF : tc;
                psum += msk ? 0.0f : __expf(tc);
            }
            float4 s = {uc[0], uc[1], uc[2], uc[3]};
            *reinterpret_cast<float4*>(urow + col) = s;
        }
        psum += __shfl_xor(psum, 1);
        psum += __shfl_xor(psum, 2);
        psum += __shfl_xor(psum, 4);
        psum += __shfl_xor(psum, 8);
        psum += __shfl_xor(psum, 16);
        float lse = __logf(fmaxf(psum, 1e-30f));
        float lse0 = __shfl(lse, 0);    // row 2w
        float lse1 = __shfl(lse, 32);   // row 2w+1

        // pass 2: full-wave stores; wave w owns rows 2w, 2w+1 (it wrote them in pass 1)
        float* obase = out + ((size_t)b * 1024 + brow + m * 16) * 1024;
#pragma unroll
        for (int rr = 0; rr < 2; rr++) {
            int r2 = w * 2 + rr;
            float lser = rr ? lse1 : lse0;
            const float* ur2 = ulds + r2 * RS;
            float* orow = obase + (size_t)r2 * 1024;
#pragma unroll
            for (int i2 = 0; i2 < 4; i2++) {
                int col = lane * 4 + i2 * 256;
                float4 u4 = *reinterpret_cast<const float4*>(ur2 + col);
                float4 o = {u4.x - lser, u4.y - lser, u4.z - lser, u4.w - lser};
                *reinterpret_cast<float4*>(orow + col) = o;
            }
        }
    }
}

extern "C" void kernel_launch(void* const* d_in, const int* in_sizes, int n_in,
                              void* d_out, int out_size, void* d_ws, size_t ws_size,
                              hipStream_t stream) {
    const float* q  = (const float*)d_in[0];
    const float* k  = (const float*)d_in[1];
    const float* wq = (const float*)d_in[2];
    const float* wk = (const float*)d_in[3];
    const int* mask = (const int*)d_in[4];
    float* out = (float*)d_out;

    char* ws = (char*)d_ws;
    short* wtq = (short*)ws;                                  // 128KB
    short* wtk = (short*)(ws + 131072);                       // 128KB
    short* Qb  = (short*)(ws + 262144);                       // 32MB
    short* Kb  = (short*)(ws + 262144 + 33554432);            // 32MB

    wtrans_kernel<<<dim3(8, 8, 2), dim3(32, 8), 0, stream>>>(wq, wk, wtq, wtk);
    proj_kernel<<<dim3(1024, 2), 512, 0, stream>>>(q, k, wtq, wtk, Qb, Kb);
    attn_kernel<<<dim3(2048), 512, 0, stream>>>(Qb, Kb, mask, out);
}

// Round 5
// 256.049 us; speedup vs baseline: 1.3934x; 1.3934x over previous
//
#include <hip/hip_runtime.h>
#include <hip/hip_bf16.h>
#include <stdint.h>

#define NEG_INF -100000000.0f

typedef __attribute__((ext_vector_type(8))) short bf16x8;
typedef __attribute__((ext_vector_type(4))) float f32x4;
typedef __attribute__((ext_vector_type(4))) int i32x4;

static __device__ __forceinline__ short f2bf(float x) {
    unsigned u = __float_as_uint(x);
    u = u + 0x7FFFu + ((u >> 16) & 1u);
    return (short)(u >> 16);
}

// ---------------- kernel 1: transpose + bf16-convert weights ----------------
// w [256 k][256 c] f32  ->  wt [256 c][256 k] bf16
// w_query additionally scaled by 1/16 (= 1/sqrt(D), exact in bf16).
__global__ void wtrans_kernel(const float* __restrict__ wq, const float* __restrict__ wk,
                              short* __restrict__ wtq, short* __restrict__ wtk) {
    __shared__ float tile[32][33];
    const float* w = blockIdx.z ? wk : wq;
    short* wt = blockIdx.z ? wtk : wtq;
    float scale = blockIdx.z ? 1.0f : 0.0625f;
    int tx = threadIdx.x, ty = threadIdx.y;
    int c0 = blockIdx.x * 32;
    int k0 = blockIdx.y * 32;
#pragma unroll
    for (int i = 0; i < 4; i++)
        tile[ty + i * 8][tx] = w[(k0 + ty + i * 8) * 256 + c0 + tx];
    __syncthreads();
#pragma unroll
    for (int i = 0; i < 4; i++)
        wt[(c0 + ty + i * 8) * 256 + k0 + tx] = f2bf(tile[tx][ty + i * 8] * scale);
}

// ---------------- kernel 2: projection GEMM  X[65536,256] @ W[256,256] -> bf16 ----------------
// Output layout MFMA-fragment swizzled: [b 64][dc 8][row 1024][ks 32] bf16
__global__ __launch_bounds__(512, 4)
void proj_kernel(const float* __restrict__ qin, const float* __restrict__ kin,
                 const short* __restrict__ wtq, const short* __restrict__ wtk,
                 short* __restrict__ Qb, short* __restrict__ Kb) {
    const float* x  = blockIdx.y ? kin : qin;
    const short* wt = blockIdx.y ? wtk : wtq;   // [c 256][k 256] bf16
    short* outp     = blockIdx.y ? Kb  : Qb;

    __shared__ __align__(16) short sbuf[64 * 296];   // staging + dump overlay
    short* xlds = sbuf;                // [64 row][32 k]
    short* wlds = sbuf + 2048;         // [256 c][32 k]

    int t = threadIdx.x;
    int lane = t & 63, w = t >> 6;
    int l15 = lane & 15, g = lane >> 4;
    int rowbase = blockIdx.x * 64;

    f32x4 zero = {0.f, 0.f, 0.f, 0.f};
    f32x4 acc[4][2];
#pragma unroll
    for (int m = 0; m < 4; m++)
#pragma unroll
        for (int n = 0; n < 2; n++) acc[m][n] = zero;

    for (int dc = 0; dc < 8; dc++) {
        __syncthreads();
        {
            int row = t >> 3, seg = t & 7;
            // non-temporal: q/k are read-once streams, keep them out of LLC
            f32x4 v = __builtin_nontemporal_load(
                reinterpret_cast<const f32x4*>(x + (size_t)(rowbase + row) * 256 + dc * 32 + seg * 4));
            short4 bb;
            bb.x = f2bf(v.x); bb.y = f2bf(v.y); bb.z = f2bf(v.z); bb.w = f2bf(v.w);
            *reinterpret_cast<short4*>(&xlds[row * 32 + seg * 4]) = bb;
        }
#pragma unroll
        for (int i = 0; i < 2; i++) {
            int idx = i * 512 + t;
            int c = idx >> 2, seg = idx & 3;
            int4 v = *reinterpret_cast<const int4*>(wt + c * 256 + dc * 32 + seg * 8);
            *reinterpret_cast<int4*>(&wlds[idx * 8]) = v;
        }
        __syncthreads();

        bf16x8 a[4], bfr[2];
#pragma unroll
        for (int m = 0; m < 4; m++)
            a[m] = *reinterpret_cast<const bf16x8*>(&xlds[(m * 16 + l15) * 32 + g * 8]);
#pragma unroll
        for (int n = 0; n < 2; n++) {
            int c = w * 32 + n * 16 + l15;
            bfr[n] = *reinterpret_cast<const bf16x8*>(&wlds[c * 32 + g * 8]);
        }
#pragma unroll
        for (int m = 0; m < 4; m++)
#pragma unroll
            for (int n = 0; n < 2; n++)
                acc[m][n] = __builtin_amdgcn_mfma_f32_16x16x32_bf16(a[m], bfr[n], acc[m][n], 0, 0, 0);
    }

    // dump C tile [64 row][256 col] bf16 to LDS (row stride 296 shorts)
    __syncthreads();
#pragma unroll
    for (int m = 0; m < 4; m++)
#pragma unroll
        for (int n = 0; n < 2; n++) {
            int col = w * 32 + n * 16 + l15;
#pragma unroll
            for (int r = 0; r < 4; r++)
                sbuf[(m * 16 + g * 4 + r) * 296 + col] = f2bf(acc[m][n][r]);
        }
    __syncthreads();

    // write out: contiguous 16B units
    int b8 = rowbase >> 10;
    int rloc = rowbase & 1023;
#pragma unroll
    for (int o = 0; o < 4; o++) {
        int gu = o * 512 + t;
        int dc = gu >> 8;
        int rem = gu & 255;
        int row = rem >> 2, kseg = rem & 3;
        int4 v = *reinterpret_cast<const int4*>(&sbuf[row * 296 + dc * 32 + kseg * 8]);
        size_t idx = (((size_t)b8 * 8 + dc) * 1024 + rloc + row) * 32 + kseg * 8;
        *reinterpret_cast<int4*>(outp + idx) = v;
    }
}

// ---------------- kernel 3: fused QK^T + tanh-clip + mask + log_softmax ----------------
__global__ __launch_bounds__(512, 4)
void attn_kernel(const short* __restrict__ Qs, const short* __restrict__ Ks,
                 const int* __restrict__ mask, float* __restrict__ out) {
    const int RS = 1028;                               // padded row stride (floats)
    __shared__ __align__(16) float ulds[16 * RS];      // ~64.3KB -> 2 blocks/CU

    int t = threadIdx.x;
    int lane = t & 63, w = t >> 6;
    int l15 = lane & 15, g = lane >> 4;

    int bid = blockIdx.x;
    int wg = (bid & 7) * 256 + (bid >> 3);
    int b = wg >> 5;
    int brow = (wg & 31) * 32;

    const short* qb = Qs + (size_t)b * 8 * 1024 * 32;
    const short* kb = Ks + (size_t)b * 8 * 1024 * 32;

    f32x4 zero = {0.f, 0.f, 0.f, 0.f};
    f32x4 acc[2][8];
#pragma unroll
    for (int m = 0; m < 2; m++)
#pragma unroll
        for (int n = 0; n < 8; n++) acc[m][n] = zero;

    for (int dc = 0; dc < 8; dc++) {
        const short* qc = qb + (size_t)dc * 1024 * 32;
        const short* kc = kb + (size_t)dc * 1024 * 32;
        bf16x8 a0 = *reinterpret_cast<const bf16x8*>(qc + (brow + l15) * 32 + g * 8);
        bf16x8 a1 = *reinterpret_cast<const bf16x8*>(qc + (brow + 16 + l15) * 32 + g * 8);
#pragma unroll
        for (int n = 0; n < 8; n++) {
            bf16x8 bf = *reinterpret_cast<const bf16x8*>(kc + (w * 128 + n * 16 + l15) * 32 + g * 8);
            acc[0][n] = __builtin_amdgcn_mfma_f32_16x16x32_bf16(a0, bf, acc[0][n], 0, 0, 0);
            acc[1][n] = __builtin_amdgcn_mfma_f32_16x16x32_bf16(a1, bf, acc[1][n], 0, 0, 0);
        }
    }

    int row = t >> 5;          // 0..15 within half-tile
    int j = t & 31;
    float* urow = ulds + row * RS;

#pragma unroll
    for (int m = 0; m < 2; m++) {
        __syncthreads();   // prior half's LDS reads (pass2) complete
        // dump fragments -> LDS U[16][1024] (padded rows)
#pragma unroll
        for (int n = 0; n < 8; n++)
#pragma unroll
            for (int r = 0; r < 4; r++)
                ulds[(g * 4 + r) * RS + w * 128 + n * 16 + l15] = acc[m][n][r];
        __syncthreads();

        const int* mrow = mask + ((size_t)b * 1024 + brow + m * 16 + row) * 1024;

        // pass 1: tanh-clip + mask + exp-sum; park uc back in LDS
        float psum = 0.f;
#pragma unroll
        for (int i = 0; i < 8; i++) {
            int col = j * 4 + i * 128;
            int4 mv = *reinterpret_cast<const int4*>(mrow + col);
            float4 u4 = *reinterpret_cast<const float4*>(urow + col);
            float uv[4] = {u4.x, u4.y, u4.z, u4.w};
            int mvv[4] = {mv.x, mv.y, mv.z, mv.w};
            float uc[4];
#pragma unroll
            for (int c = 0; c < 4; c++) {
                float e2 = __expf(2.0f * uv[c]);
                float tc = 10.0f - 20.0f / (e2 + 1.0f);   // 10*tanh(u)
                bool msk = (mvv[c] == 1);
                uc[c] = msk ? NEG_INF : tc;
                psum += msk ? 0.0f : __expf(tc);
            }
            float4 s = {uc[0], uc[1], uc[2], uc[3]};
            *reinterpret_cast<float4*>(urow + col) = s;
        }
        psum += __shfl_xor(psum, 1);
        psum += __shfl_xor(psum, 2);
        psum += __shfl_xor(psum, 4);
        psum += __shfl_xor(psum, 8);
        psum += __shfl_xor(psum, 16);
        float lse = __logf(fmaxf(psum, 1e-30f));
        float lse0 = __shfl(lse, 0);    // row 2w
        float lse1 = __shfl(lse, 32);   // row 2w+1

        // pass 2: full-wave non-temporal stores; wave w owns rows 2w, 2w+1
        float* obase = out + ((size_t)b * 1024 + brow + m * 16) * 1024;
#pragma unroll
        for (int rr = 0; rr < 2; rr++) {
            int r2 = w * 2 + rr;
            float lser = rr ? lse1 : lse0;
            const float* ur2 = ulds + r2 * RS;
            float* orow = obase + (size_t)r2 * 1024;
#pragma unroll
            for (int i2 = 0; i2 < 4; i2++) {
                int col = lane * 4 + i2 * 256;
                float4 u4 = *reinterpret_cast<const float4*>(ur2 + col);
                f32x4 o = {u4.x - lser, u4.y - lser, u4.z - lser, u4.w - lser};
                __builtin_nontemporal_store(o, reinterpret_cast<f32x4*>(orow + col));
            }
        }
    }
}

extern "C" void kernel_launch(void* const* d_in, const int* in_sizes, int n_in,
                              void* d_out, int out_size, void* d_ws, size_t ws_size,
                              hipStream_t stream) {
    const float* q  = (const float*)d_in[0];
    const float* k  = (const float*)d_in[1];
    const float* wq = (const float*)d_in[2];
    const float* wk = (const float*)d_in[3];
    const int* mask = (const int*)d_in[4];
    float* out = (float*)d_out;

    char* ws = (char*)d_ws;
    short* wtq = (short*)ws;                                  // 128KB
    short* wtk = (short*)(ws + 131072);                       // 128KB
    short* Qb  = (short*)(ws + 262144);                       // 32MB
    short* Kb  = (short*)(ws + 262144 + 33554432);            // 32MB

    wtrans_kernel<<<dim3(8, 8, 2), dim3(32, 8), 0, stream>>>(wq, wk, wtq, wtk);
    proj_kernel<<<dim3(1024, 2), 512, 0, stream>>>(q, k, wtq, wtk, Qb, Kb);
    attn_kernel<<<dim3(2048), 512, 0, stream>>>(Qb, Kb, mask, out);
}

// Round 6
// 246.998 us; speedup vs baseline: 1.4445x; 1.0366x over previous
//
#include <hip/hip_runtime.h>
#include <hip/hip_bf16.h>
#include <stdint.h>

#define NEG_INF -100000000.0f

typedef __attribute__((ext_vector_type(8))) short bf16x8;
typedef __attribute__((ext_vector_type(4))) float f32x4;

static __device__ __forceinline__ short f2bf(float x) {
    unsigned u = __float_as_uint(x);
    u = u + 0x7FFFu + ((u >> 16) & 1u);
    return (short)(u >> 16);
}

// ---------------- kernel 1: transpose + bf16-convert weights ----------------
__global__ void wtrans_kernel(const float* __restrict__ wq, const float* __restrict__ wk,
                              short* __restrict__ wtq, short* __restrict__ wtk) {
    __shared__ float tile[32][33];
    const float* w = blockIdx.z ? wk : wq;
    short* wt = blockIdx.z ? wtk : wtq;
    float scale = blockIdx.z ? 1.0f : 0.0625f;
    int tx = threadIdx.x, ty = threadIdx.y;
    int c0 = blockIdx.x * 32;
    int k0 = blockIdx.y * 32;
#pragma unroll
    for (int i = 0; i < 4; i++)
        tile[ty + i * 8][tx] = w[(k0 + ty + i * 8) * 256 + c0 + tx];
    __syncthreads();
#pragma unroll
    for (int i = 0; i < 4; i++)
        wt[(c0 + ty + i * 8) * 256 + k0 + tx] = f2bf(tile[tx][ty + i * 8] * scale);
}

// ---------------- kernel 1b: bit-pack mask ----------------
// word (row, j) holds bit (i*4+c) = mask[row][j*4 + i*128 + c], matching the
// attn epilogue's traversal exactly. 268MB -> 8.4MB.
__global__ __launch_bounds__(256)
void maskpack_kernel(const int* __restrict__ mask, unsigned* __restrict__ pmask) {
    int t = threadIdx.x;
    int j = t & 31;
    size_t row = (size_t)blockIdx.x * 8 + (t >> 5);
    const int* mrow = mask + row * 1024 + j * 4;
    unsigned v = 0;
#pragma unroll
    for (int i = 0; i < 8; i++) {
        int4 x = *reinterpret_cast<const int4*>(mrow + i * 128);
        unsigned nib = (unsigned)(x.x | (x.y << 1) | (x.z << 2) | (x.w << 3));
        v |= nib << (i * 4);
    }
    pmask[row * 32 + j] = v;
}

// ---------------- kernel 2: projection GEMM  X[65536,256] @ W[256,256] -> bf16 ----------------
// Output layout MFMA-fragment swizzled: [b 64][dc 8][row 1024][ks 32] bf16
__global__ __launch_bounds__(512, 4)
void proj_kernel(const float* __restrict__ qin, const float* __restrict__ kin,
                 const short* __restrict__ wtq, const short* __restrict__ wtk,
                 short* __restrict__ Qb, short* __restrict__ Kb) {
    const float* x  = blockIdx.y ? kin : qin;
    const short* wt = blockIdx.y ? wtk : wtq;
    short* outp     = blockIdx.y ? Kb  : Qb;

    __shared__ __align__(16) short sbuf[64 * 296];
    short* xlds = sbuf;                // [64 row][32 k]
    short* wlds = sbuf + 2048;         // [256 c][32 k]

    int t = threadIdx.x;
    int lane = t & 63, w = t >> 6;
    int l15 = lane & 15, g = lane >> 4;
    int rowbase = blockIdx.x * 64;

    f32x4 zero = {0.f, 0.f, 0.f, 0.f};
    f32x4 acc[4][2];
#pragma unroll
    for (int m = 0; m < 4; m++)
#pragma unroll
        for (int n = 0; n < 2; n++) acc[m][n] = zero;

    for (int dc = 0; dc < 8; dc++) {
        __syncthreads();
        {
            int row = t >> 3, seg = t & 7;
            f32x4 v = __builtin_nontemporal_load(
                reinterpret_cast<const f32x4*>(x + (size_t)(rowbase + row) * 256 + dc * 32 + seg * 4));
            short4 bb;
            bb.x = f2bf(v.x); bb.y = f2bf(v.y); bb.z = f2bf(v.z); bb.w = f2bf(v.w);
            *reinterpret_cast<short4*>(&xlds[row * 32 + seg * 4]) = bb;
        }
#pragma unroll
        for (int i = 0; i < 2; i++) {
            int idx = i * 512 + t;
            int c = idx >> 2, seg = idx & 3;
            int4 v = *reinterpret_cast<const int4*>(wt + c * 256 + dc * 32 + seg * 8);
            *reinterpret_cast<int4*>(&wlds[idx * 8]) = v;
        }
        __syncthreads();

        bf16x8 a[4], bfr[2];
#pragma unroll
        for (int m = 0; m < 4; m++)
            a[m] = *reinterpret_cast<const bf16x8*>(&xlds[(m * 16 + l15) * 32 + g * 8]);
#pragma unroll
        for (int n = 0; n < 2; n++) {
            int c = w * 32 + n * 16 + l15;
            bfr[n] = *reinterpret_cast<const bf16x8*>(&wlds[c * 32 + g * 8]);
        }
#pragma unroll
        for (int m = 0; m < 4; m++)
#pragma unroll
            for (int n = 0; n < 2; n++)
                acc[m][n] = __builtin_amdgcn_mfma_f32_16x16x32_bf16(a[m], bfr[n], acc[m][n], 0, 0, 0);
    }

    __syncthreads();
#pragma unroll
    for (int m = 0; m < 4; m++)
#pragma unroll
        for (int n = 0; n < 2; n++) {
            int col = w * 32 + n * 16 + l15;
#pragma unroll
            for (int r = 0; r < 4; r++)
                sbuf[(m * 16 + g * 4 + r) * 296 + col] = f2bf(acc[m][n][r]);
        }
    __syncthreads();

    int b8 = rowbase >> 10;
    int rloc = rowbase & 1023;
#pragma unroll
    for (int o = 0; o < 4; o++) {
        int gu = o * 512 + t;
        int dc = gu >> 8;
        int rem = gu & 255;
        int row = rem >> 2, kseg = rem & 3;
        int4 v = *reinterpret_cast<const int4*>(&sbuf[row * 296 + dc * 32 + kseg * 8]);
        size_t idx = (((size_t)b8 * 8 + dc) * 1024 + rloc + row) * 32 + kseg * 8;
        *reinterpret_cast<int4*>(outp + idx) = v;
    }
}

// ---------------- kernel 3: fused QK^T + tanh-clip + mask + log_softmax ----------------
__global__ __launch_bounds__(512, 4)
void attn_kernel(const short* __restrict__ Qs, const short* __restrict__ Ks,
                 const unsigned* __restrict__ pmask, float* __restrict__ out) {
    const int RS = 1028;                               // padded row stride (floats)
    __shared__ __align__(16) float ulds[16 * RS];      // ~64.3KB -> 2 blocks/CU

    int t = threadIdx.x;
    int lane = t & 63, w = t >> 6;
    int l15 = lane & 15, g = lane >> 4;

    int bid = blockIdx.x;
    int wg = (bid & 7) * 256 + (bid >> 3);
    int b = wg >> 5;
    int brow = (wg & 31) * 32;

    // packed-mask prefetch: 2 scalar uints per thread, consumed only in the
    // epilogue -> fully hidden behind QK^T. pm[m*512 + t] is contiguous.
    const unsigned* pm = pmask + ((size_t)b * 1024 + brow) * 32;
    unsigned mbits0 = pm[t];
    unsigned mbits1 = pm[512 + t];

    const short* qb = Qs + (size_t)b * 8 * 1024 * 32;
    const short* kb = Ks + (size_t)b * 8 * 1024 * 32;

    f32x4 zero = {0.f, 0.f, 0.f, 0.f};
    f32x4 acc[2][8];
#pragma unroll
    for (int m = 0; m < 2; m++)
#pragma unroll
        for (int n = 0; n < 8; n++) acc[m][n] = zero;

    for (int dc = 0; dc < 8; dc++) {
        const short* qc = qb + (size_t)dc * 1024 * 32;
        const short* kc = kb + (size_t)dc * 1024 * 32;
        bf16x8 a0 = *reinterpret_cast<const bf16x8*>(qc + (brow + l15) * 32 + g * 8);
        bf16x8 a1 = *reinterpret_cast<const bf16x8*>(qc + (brow + 16 + l15) * 32 + g * 8);
#pragma unroll
        for (int n = 0; n < 8; n++) {
            bf16x8 bf = *reinterpret_cast<const bf16x8*>(kc + (w * 128 + n * 16 + l15) * 32 + g * 8);
            acc[0][n] = __builtin_amdgcn_mfma_f32_16x16x32_bf16(a0, bf, acc[0][n], 0, 0, 0);
            acc[1][n] = __builtin_amdgcn_mfma_f32_16x16x32_bf16(a1, bf, acc[1][n], 0, 0, 0);
        }
    }

    int row = t >> 5;          // 0..15 within half-tile
    int j = t & 31;
    float* urow = ulds + row * RS;

#pragma unroll
    for (int m = 0; m < 2; m++) {
        __syncthreads();   // prior half's LDS reads (pass2) complete
        // dump fragments -> LDS U[16][1024] (padded rows)
#pragma unroll
        for (int n = 0; n < 8; n++)
#pragma unroll
            for (int r = 0; r < 4; r++)
                ulds[(g * 4 + r) * RS + w * 128 + n * 16 + l15] = acc[m][n][r];
        __syncthreads();

        unsigned bits = m ? mbits1 : mbits0;

        // pass 1: tanh-clip + mask + exp-sum; park uc back in LDS. No global loads.
        float psum = 0.f;
#pragma unroll
        for (int i = 0; i < 8; i++) {
            int col = j * 4 + i * 128;
            float4 u4 = *reinterpret_cast<const float4*>(urow + col);
            float uv[4] = {u4.x, u4.y, u4.z, u4.w};
            float uc[4];
#pragma unroll
            for (int c = 0; c < 4; c++) {
                float e2 = __expf(2.0f * uv[c]);
                float tc = 10.0f - 20.0f / (e2 + 1.0f);   // 10*tanh(u)
                bool msk = (bits >> (i * 4 + c)) & 1;
                uc[c] = msk ? NEG_INF : tc;
                psum += msk ? 0.0f : __expf(tc);
            }
            float4 s = {uc[0], uc[1], uc[2], uc[3]};
            *reinterpret_cast<float4*>(urow + col) = s;
        }
        psum += __shfl_xor(psum, 1);
        psum += __shfl_xor(psum, 2);
        psum += __shfl_xor(psum, 4);
        psum += __shfl_xor(psum, 8);
        psum += __shfl_xor(psum, 16);
        float lse = __logf(fmaxf(psum, 1e-30f));
        float lse0 = __shfl(lse, 0);    // row 2w
        float lse1 = __shfl(lse, 32);   // row 2w+1

        // pass 2: full-wave non-temporal stores; wave w owns rows 2w, 2w+1
        float* obase = out + ((size_t)b * 1024 + brow + m * 16) * 1024;
#pragma unroll
        for (int rr = 0; rr < 2; rr++) {
            int r2 = w * 2 + rr;
            float lser = rr ? lse1 : lse0;
            const float* ur2 = ulds + r2 * RS;
            float* orow = obase + (size_t)r2 * 1024;
#pragma unroll
            for (int i2 = 0; i2 < 4; i2++) {
                int col = lane * 4 + i2 * 256;
                float4 u4 = *reinterpret_cast<const float4*>(ur2 + col);
                f32x4 o = {u4.x - lser, u4.y - lser, u4.z - lser, u4.w - lser};
                __builtin_nontemporal_store(o, reinterpret_cast<f32x4*>(orow + col));
            }
        }
    }
}

extern "C" void kernel_launch(void* const* d_in, const int* in_sizes, int n_in,
                              void* d_out, int out_size, void* d_ws, size_t ws_size,
                              hipStream_t stream) {
    const float* q  = (const float*)d_in[0];
    const float* k  = (const float*)d_in[1];
    const float* wq = (const float*)d_in[2];
    const float* wk = (const float*)d_in[3];
    const int* mask = (const int*)d_in[4];
    float* out = (float*)d_out;

    char* ws = (char*)d_ws;
    short* wtq = (short*)ws;                                  // 128KB
    short* wtk = (short*)(ws + 131072);                       // 128KB
    short* Qb  = (short*)(ws + 262144);                       // 32MB
    short* Kb  = (short*)(ws + 262144 + 33554432);            // 32MB
    unsigned* pmask = (unsigned*)(ws + 262144 + 2 * 33554432); // 8.4MB

    wtrans_kernel<<<dim3(8, 8, 2), dim3(32, 8), 0, stream>>>(wq, wk, wtq, wtk);
    maskpack_kernel<<<dim3(8192), 256, 0, stream>>>(mask, pmask);
    proj_kernel<<<dim3(1024, 2), 512, 0, stream>>>(q, k, wtq, wtk, Qb, Kb);
    attn_kernel<<<dim3(2048), 512, 0, stream>>>(Qb, Kb, pmask, out);
}